// Round 24
// baseline (296.055 us; speedup 1.0000x reference)
//
#include <hip/hip_runtime.h>
#include <math.h>

// Problem constants: B=4, C=64, H=256, W=256, L=2, M1=M2=32, HM=128, P=256, O=1

// workspace layout (in floats)
#define OFF_XA   0                      // bf16 XA4: ushort[16777216], [c/4][px][4] interleave
#define OFF_XB   16777216               // bf16 XBb planar [16777216] + XB4 interleave [16777216]
#define OFF_Z1   33554432               // 4194304 floats: X1 (4M) OR Zre(2M)+Zim(2M)
#define OFF_XF   37748736               // XFre 524288 + XFim 524288
#define OFF_OF   38797312               // OFT 1048576  [plane][kx][2j+d]
#define OFF_TBF  39845888               // ushort[16384] invW twiddle Tt[w][k]
#define OFF_EH   39854080               // ushort[16384] fwdW E_hi[n][w]
#define OFF_EL   39862272               // ushort[16384] fwdW E_lo[n][w]
#define OFF_AFH  39870464               // ushort[65536] fwdH A_hi[n=128][k=512]
#define OFF_AFL  39903232               // ushort[65536] fwdH A_lo
#define OFF_AIH  39936000               // ushort[65536] invH A_hi[c=2][h=256][k=128]
#define OFF_AIL  39968768               // ushort[65536] invH A_lo
#define OFF_WBF  40001536               // ushort[65536] bf16 weights
// total = 40034304 floats ≈ 152.7 MiB

// WB (ushort) layout: [0:16384) mlp_w1 | [16384:32768) mlp_w2 | [32768:40960) mlp_skip_w
//                     [40960:57344) proj_w1 | [57344:65536) spectral skip_w (2x64x64)
// Interleave-4 activation layout: act[b*4194304 + (c>>2)*262144 + px*4 + (c&3)].

typedef __attribute__((ext_vector_type(8))) short short8b;   // 8 bf16 (4 VGPRs)
typedef __attribute__((ext_vector_type(4))) float f32x4;     // MFMA acc

// GELU via exp2-folded sigmoid form
__device__ __forceinline__ float gelu_f(float v) {
    float nu = v * fmaf(v * v, -0.10294345f, -2.3022078f);
    float e;
    asm("v_exp_f32 %0, %1" : "=v"(e) : "v"(nu));
    return v * __builtin_amdgcn_rcpf(1.0f + e);
}

__device__ __forceinline__ unsigned f2bf(float f) {
    unsigned int u = __float_as_uint(f);
    u += 0x7FFFu + ((u >> 16) & 1u);   // RNE
    return u >> 16;
}

// one-instruction convert+pack: lo16 = bf16(a), hi16 = bf16(b)
__device__ __forceinline__ unsigned cvtpk(float a, float b) {
    unsigned r;
    asm("v_cvt_pk_bf16_f32 %0, %1, %2" : "=v"(r) : "v"(a), "v"(b));
    return r;
}

// load an 8-channel frag from interleave-4 layout: 2x 8B loads
__device__ __forceinline__ short8b ld_frag_i4(const unsigned short* base, int ch0, int px) {
    const uint2* p0 = (const uint2*)(base + (size_t)(ch0 >> 2) * 262144 + px * 4);
    const uint2* p1 = (const uint2*)(base + (size_t)((ch0 >> 2) + 1) * 262144 + px * 4);
    uint2 lo = *p0, hi = *p1;
    uint4 pk = {lo.x, lo.y, hi.x, hi.y};
    return *(short8b*)&pk;
}

__global__ __launch_bounds__(256) void init_tw(float* ws) {
    int idx = blockIdx.x * 256 + threadIdx.x;
    unsigned short* tbf = (unsigned short*)(ws + OFF_TBF);
    unsigned short* eh  = (unsigned short*)(ws + OFF_EH);
    unsigned short* el  = (unsigned short*)(ws + OFF_EL);
    unsigned short* afh = (unsigned short*)(ws + OFF_AFH);
    unsigned short* afl = (unsigned short*)(ws + OFF_AFL);
    unsigned short* aih = (unsigned short*)(ws + OFF_AIH);
    unsigned short* ail = (unsigned short*)(ws + OFF_AIL);
    const double PI128 = 3.14159265358979323846 / 128.0;
    if (idx < 16384) {
        int w = idx >> 6, k = idx & 63;
        int kx = k >> 1;
        int m = (kx * w) & 255;
        double a = (double)m * PI128;
        float sc = (kx == 0) ? (1.0f / 65536.0f) : (2.0f / 65536.0f);
        float v = (k & 1) ? (float)(-sin(a)) * sc : (float)cos(a) * sc;
        tbf[idx] = (unsigned short)f2bf(v);
    }
    int i2 = idx - 16384;
    if (i2 >= 0 && i2 < 16384) {
        int n = i2 >> 8, w = i2 & 255;
        int kx = n >> 1;
        int m = (kx * w) & 255;
        double a = (double)m * PI128;
        float v = (n & 1) ? (float)(-sin(a)) : (float)cos(a);
        unsigned h = f2bf(v);
        eh[i2] = (unsigned short)h;
        el[i2] = (unsigned short)f2bf(v - __uint_as_float(h << 16));
    }
    int i3 = idx - 32768;
    if (i3 >= 0 && i3 < 65536) {
        int n = i3 >> 9, k = i3 & 511;
        int j = n & 63, c = n >> 6;
        int h = k >> 1, d = k & 1;
        int ky = (j < 32) ? j : (192 + j);
        int m = (ky * h) & 255;
        double a = (double)m * PI128;
        float cv = (float)cos(a), sv = (float)sin(a);
        float v = (c == 0) ? (d ? sv : cv) : (d ? cv : -sv);
        unsigned hh = f2bf(v);
        afh[i3] = (unsigned short)hh;
        afl[i3] = (unsigned short)f2bf(v - __uint_as_float(hh << 16));
    }
    int i4 = idx - 98304;
    if (i4 >= 0 && i4 < 65536) {
        int c = i4 >> 15, rem = i4 & 32767;
        int h = rem >> 7, k = rem & 127;
        int j = k >> 1, d = k & 1;
        int ky = (j < 32) ? j : (192 + j);
        int m = (ky * h) & 255;
        double a = (double)m * PI128;
        float cv = (float)cos(a), sv = (float)sin(a);
        float v = (c == 0) ? (d ? -sv : cv) : (d ? cv : sv);
        unsigned hh = f2bf(v);
        aih[i4] = (unsigned short)hh;
        ail[i4] = (unsigned short)f2bf(v - __uint_as_float(hh << 16));
    }
}

__global__ __launch_bounds__(256) void k_cvt(const float* __restrict__ w1,
                                             const float* __restrict__ w2,
                                             const float* __restrict__ wsk,
                                             const float* __restrict__ pw1,
                                             const float* __restrict__ ssk,
                                             unsigned short* __restrict__ wb) {
    int idx = blockIdx.x * 256 + threadIdx.x;
    if (idx < 16384)       wb[idx] = (unsigned short)f2bf(w1[idx]);
    else if (idx < 32768)  wb[idx] = (unsigned short)f2bf(w2[idx - 16384]);
    else if (idx < 40960)  wb[idx] = (unsigned short)f2bf(wsk[idx - 32768]);
    else if (idx < 57344)  wb[idx] = (unsigned short)f2bf(pw1[idx - 40960]);
    else if (idx < 65536)  wb[idx] = (unsigned short)f2bf(ssk[idx - 57344]);
}

// ---- MFMA fwd-W DFT, fp32 input (layer 0), split-bf16 3-pass.
// Twiddle tables LDS-staged (64 KB, XOR-swizzled).
__global__ __launch_bounds__(256) void k_fwd_w_f32(const float* __restrict__ x,
                                                   float* __restrict__ X1f,
                                                   const unsigned short* __restrict__ EH,
                                                   const unsigned short* __restrict__ EL) {
    __shared__ __align__(16) unsigned short smEH[16384];   // 32 KB [n][w-oct swizzled]
    __shared__ __align__(16) unsigned short smEL[16384];   // 32 KB
    int t = threadIdx.x;
#pragma unroll
    for (int pass = 0; pass < 8; ++pass) {
        int g = pass * 256 + t;               // 16B granule: row=g>>5, oct=g&31
        int rown = g >> 5, oct = g & 31;
        int dst = rown * 256 + ((oct ^ (rown & 7)) * 8);
        *(uint4*)&smEH[dst] = *(const uint4*)&EH[g * 8];
        *(uint4*)&smEL[dst] = *(const uint4*)&EL[g * 8];
    }
    __syncthreads();

    int lane = t & 63, wv = t >> 6;
    int col = lane & 15, grp = lane >> 4;
    size_t row0 = (size_t)blockIdx.x * 64;
    int row = wv * 16 + col;
    const float* rp = x + (row0 + row) * 256 + grp * 8;

    short8b bH[8], bL[8];
#pragma unroll
    for (int kb = 0; kb < 8; ++kb) {
        float4 v0 = *(const float4*)(rp + kb * 32);
        float4 v1 = *(const float4*)(rp + kb * 32 + 4);
        float vv[8] = {v0.x, v0.y, v0.z, v0.w, v1.x, v1.y, v1.z, v1.w};
        short8b vH, vL;
#pragma unroll
        for (int i = 0; i < 8; ++i) {
            unsigned h = f2bf(vv[i]);
            vH[i] = (short)h;
            vL[i] = (short)f2bf(vv[i] - __uint_as_float(h << 16));
        }
        bH[kb] = vH; bL[kb] = vL;
    }
#pragma unroll
    for (int ot = 0; ot < 4; ++ot) {
        int n = ot * 16 + col;
        const unsigned short* eh = &smEH[n * 256];
        const unsigned short* el = &smEL[n * 256];
        f32x4 acc = {0.f, 0.f, 0.f, 0.f};
#pragma unroll
        for (int kb = 0; kb < 8; ++kb) {
            int off = ((kb * 4 + grp) ^ (n & 7)) * 8;
            const short8b aH = *(const short8b*)&eh[off];
            const short8b aL = *(const short8b*)&el[off];
            acc = __builtin_amdgcn_mfma_f32_16x16x32_bf16(aH, bH[kb], acc, 0, 0, 0);
            acc = __builtin_amdgcn_mfma_f32_16x16x32_bf16(aH, bL[kb], acc, 0, 0, 0);
            acc = __builtin_amdgcn_mfma_f32_16x16x32_bf16(aL, bH[kb], acc, 0, 0, 0);
        }
        *(float4*)&X1f[(row0 + row) * 64 + ot * 16 + grp * 4] = *(float4*)&acc;
    }
}

// ---- MFMA fwd-W DFT, bf16 input (layer 1): same LDS-staged twiddles.
__global__ __launch_bounds__(256) void k_fwd_w_bf16(const unsigned short* __restrict__ xb,
                                                    float* __restrict__ X1f,
                                                    const unsigned short* __restrict__ EH,
                                                    const unsigned short* __restrict__ EL) {
    __shared__ __align__(16) unsigned short smEH[16384];
    __shared__ __align__(16) unsigned short smEL[16384];
    int t = threadIdx.x;
#pragma unroll
    for (int pass = 0; pass < 8; ++pass) {
        int g = pass * 256 + t;
        int rown = g >> 5, oct = g & 31;
        int dst = rown * 256 + ((oct ^ (rown & 7)) * 8);
        *(uint4*)&smEH[dst] = *(const uint4*)&EH[g * 8];
        *(uint4*)&smEL[dst] = *(const uint4*)&EL[g * 8];
    }
    __syncthreads();

    int lane = t & 63, wv = t >> 6;
    int col = lane & 15, grp = lane >> 4;
    size_t row0 = (size_t)blockIdx.x * 64;
    int row = wv * 16 + col;
    const unsigned short* rp = xb + (row0 + row) * 256 + grp * 8;

    short8b bH[8];
#pragma unroll
    for (int kb = 0; kb < 8; ++kb)
        bH[kb] = *(const short8b*)(rp + kb * 32);
#pragma unroll
    for (int ot = 0; ot < 4; ++ot) {
        int n = ot * 16 + col;
        const unsigned short* eh = &smEH[n * 256];
        const unsigned short* el = &smEL[n * 256];
        f32x4 acc = {0.f, 0.f, 0.f, 0.f};
#pragma unroll
        for (int kb = 0; kb < 8; ++kb) {
            int off = ((kb * 4 + grp) ^ (n & 7)) * 8;
            const short8b aH = *(const short8b*)&eh[off];
            const short8b aL = *(const short8b*)&el[off];
            acc = __builtin_amdgcn_mfma_f32_16x16x32_bf16(aH, bH[kb], acc, 0, 0, 0);
            acc = __builtin_amdgcn_mfma_f32_16x16x32_bf16(aL, bH[kb], acc, 0, 0, 0);
        }
        *(float4*)&X1f[(row0 + row) * 64 + ot * 16 + grp * 4] = *(float4*)&acc;
    }
}

// ---- MFMA forward DFT over H, 2-pass (B=X1 as bf16; twiddle A keeps hi+lo)
__global__ __launch_bounds__(256) void k_fwd_h(const float* __restrict__ X1f,
                                               float* __restrict__ XFre,
                                               float* __restrict__ XFim,
                                               const unsigned short* __restrict__ AFH,
                                               const unsigned short* __restrict__ AFL) {
    __shared__ __align__(16) unsigned short smH[32 * 512];   // 32 KB
    int t = threadIdx.x;
    int plane = blockIdx.x;
    const float* xp = X1f + (size_t)plane * 16384;
#pragma unroll
    for (int pass = 0; pass < 16; ++pass) {
        int idx = pass * 256 + t;
        int h = idx >> 4, seg = idx & 15;
        float4 v = *(const float4*)(xp + h * 64 + seg * 4);
        int kx0 = seg * 2, kx1 = seg * 2 + 1;
        int k0 = 2 * h;
        int oct = k0 >> 3, e = k0 & 7;
        int b0 = oct ^ (kx0 & 7), b1 = oct ^ (kx1 & 7);
        *(unsigned*)&smH[kx0 * 512 + b0 * 8 + e] = cvtpk(v.x, v.y);
        *(unsigned*)&smH[kx1 * 512 + b1 * 8 + e] = cvtpk(v.z, v.w);
    }
    __syncthreads();
    int lane = t & 63, wv = t >> 6;
    int col = lane & 15, grp = lane >> 4;
#pragma unroll
    for (int mi = 0; mi < 2; ++mi) {
        int mt = wv * 2 + mi;
        const unsigned short* Ah = AFH + (mt * 16 + col) * 512;
        const unsigned short* Al = AFL + (mt * 16 + col) * 512;
        f32x4 acc0 = {0.f, 0.f, 0.f, 0.f}, acc1 = {0.f, 0.f, 0.f, 0.f};
#pragma unroll
        for (int kb = 0; kb < 16; ++kb) {
            short8b aH = *(const short8b*)&Ah[kb * 32 + grp * 8];
            short8b aL = *(const short8b*)&Al[kb * 32 + grp * 8];
#pragma unroll
            for (int nt = 0; nt < 2; ++nt) {
                int kx = nt * 16 + col;
                int blk = (kb * 4 + grp) ^ (kx & 7);
                short8b bH = *(const short8b*)&smH[kx * 512 + blk * 8];
                f32x4 a = (nt == 0) ? acc0 : acc1;
                a = __builtin_amdgcn_mfma_f32_16x16x32_bf16(aH, bH, a, 0, 0, 0);
                a = __builtin_amdgcn_mfma_f32_16x16x32_bf16(aL, bH, a, 0, 0, 0);
                if (nt == 0) acc0 = a; else acc1 = a;
            }
        }
#pragma unroll
        for (int nt = 0; nt < 2; ++nt) {
            int kx = nt * 16 + col;
            f32x4 a = (nt == 0) ? acc0 : acc1;
#pragma unroll
            for (int r = 0; r < 4; ++r) {
                int n = mt * 16 + grp * 4 + r;
                float* dst = (n < 64)
                    ? (XFre + (size_t)plane * 2048 + n * 32 + kx)
                    : (XFim + (size_t)plane * 2048 + (n - 64) * 32 + kx);
                *dst = a[r];
            }
        }
    }
}

// ---- per-mode complex matmul: 4 o's per thread (8 indep chains, 16 W loads in flight)
__global__ __launch_bounds__(128) void k_modemul(const float* __restrict__ XFre,
                                                 const float* __restrict__ XFim,
                                                 const float2* __restrict__ sw1,
                                                 const float2* __restrict__ sw2,
                                                 float* __restrict__ OFT, int l) {
    int o0 = blockIdx.x * 4, j = blockIdx.y;
    int tid = threadIdx.x;
    int kx = tid & 31, b = tid >> 5;
    int jj = (j < 32) ? j : (j - 32);
    const float2* W0 = ((j < 32) ? sw1 : sw2)
                     + (l * 4194304 + (size_t)o0 * 1024 + jj * 32 + kx);
    const float* Xr = XFre + (size_t)(b * 64) * 2048 + j * 32 + kx;
    const float* Xi = XFim + (size_t)(b * 64) * 2048 + j * 32 + kx;
    float ar[4] = {0.f, 0.f, 0.f, 0.f}, ai[4] = {0.f, 0.f, 0.f, 0.f};
#pragma unroll 4
    for (int i = 0; i < 64; ++i) {
        float xr = Xr[i * 2048], xi = Xi[i * 2048];
        const float2* Wi = W0 + (size_t)i * 65536;
#pragma unroll
        for (int q = 0; q < 4; ++q) {
            float2 w = Wi[q * 1024];
            ar[q] += xr * w.x - xi * w.y;
            ai[q] += xr * w.y + xi * w.x;
        }
    }
#pragma unroll
    for (int q = 0; q < 4; ++q) {
        float* d = OFT + (size_t)(b * 64 + o0 + q) * 4096 + kx * 128 + 2 * j;
        d[0] = ar[q];
        d[1] = ai[q];
    }
}

// ---- MFMA inverse DFT over H, 2-pass
__global__ __launch_bounds__(256) void k_inv_h(const float* __restrict__ OFT,
                                               float* __restrict__ Zre,
                                               float* __restrict__ Zim,
                                               const unsigned short* __restrict__ AIH,
                                               const unsigned short* __restrict__ AIL) {
    __shared__ __align__(16) unsigned short smH[32 * 128];   // 8 KB
    int t = threadIdx.x;
    int plane = blockIdx.x;
    const float* op = OFT + (size_t)plane * 4096;
#pragma unroll
    for (int pass = 0; pass < 4; ++pass) {
        int idx = pass * 256 + t;
        int kx = idx >> 5, seg = idx & 31;
        float4 v = *(const float4*)(op + kx * 128 + seg * 4);
        int k0 = seg * 4;
        int oct = k0 >> 3, e = k0 & 7;
        int blk = oct ^ (kx & 7);
        uint2 ph = {cvtpk(v.x, v.y), cvtpk(v.z, v.w)};
        *(uint2*)&smH[kx * 128 + blk * 8 + e] = ph;
    }
    __syncthreads();
    int lane = t & 63, wv = t >> 6;
    int col = lane & 15, grp = lane >> 4;
#pragma unroll
    for (int mi = 0; mi < 4; ++mi) {
        int mt = wv * 4 + mi;
#pragma unroll
        for (int cc = 0; cc < 2; ++cc) {
            const unsigned short* Ah = AIH + cc * 32768 + (mt * 16 + col) * 128;
            const unsigned short* Al = AIL + cc * 32768 + (mt * 16 + col) * 128;
            f32x4 acc0 = {0.f, 0.f, 0.f, 0.f}, acc1 = {0.f, 0.f, 0.f, 0.f};
#pragma unroll
            for (int kb = 0; kb < 4; ++kb) {
                short8b aH = *(const short8b*)&Ah[kb * 32 + grp * 8];
                short8b aL = *(const short8b*)&Al[kb * 32 + grp * 8];
#pragma unroll
                for (int nt = 0; nt < 2; ++nt) {
                    int kx = nt * 16 + col;
                    int blk = (kb * 4 + grp) ^ (kx & 7);
                    short8b bH = *(const short8b*)&smH[kx * 128 + blk * 8];
                    f32x4 a = (nt == 0) ? acc0 : acc1;
                    a = __builtin_amdgcn_mfma_f32_16x16x32_bf16(aH, bH, a, 0, 0, 0);
                    a = __builtin_amdgcn_mfma_f32_16x16x32_bf16(aL, bH, a, 0, 0, 0);
                    if (nt == 0) acc0 = a; else acc1 = a;
                }
            }
            float* Zc = (cc == 0) ? Zre : Zim;
#pragma unroll
            for (int nt = 0; nt < 2; ++nt) {
                int kx = nt * 16 + col;
                f32x4 a = (nt == 0) ? acc0 : acc1;
#pragma unroll
                for (int r = 0; r < 4; ++r) {
                    int h = mt * 16 + grp * 4 + r;
                    Zc[(size_t)plane * 8192 + h * 32 + kx] = a[r];
                }
            }
        }
    }
}

// ---- MFMA fused inverse-W DFT + channel skip + bias + GELU -> XA interleave-4
template<int BF16IN>
__global__ __launch_bounds__(512) void k_invw_skip(const float* __restrict__ Zre,
                                                   const float* __restrict__ Zim,
                                                   const float* __restrict__ xinf,
                                                   const unsigned short* __restrict__ xinb,
                                                   const unsigned short* __restrict__ tbf,
                                                   const unsigned short* __restrict__ wsk,
                                                   const float* __restrict__ skip_b,
                                                   unsigned short* __restrict__ xout, int l) {
    __shared__ __align__(16) unsigned short smZ[64 * 64];    // 8 KB, reused by 8 waves
    int t = threadIdx.x;
    int hh = blockIdx.x, b = blockIdx.y;

    {
        int o = t >> 3, seg = t & 7;
        const float* zr = Zre + (size_t)(b * 64 + o) * 8192 + hh * 32 + seg * 4;
        const float* zi = Zim + (size_t)(b * 64 + o) * 8192 + hh * 32 + seg * 4;
        float4 r = *(const float4*)zr;
        float4 i = *(const float4*)zi;
        uint4 pk;
        pk.x = cvtpk(r.x, i.x);
        pk.y = cvtpk(r.y, i.y);
        pk.z = cvtpk(r.z, i.z);
        pk.w = cvtpk(r.w, i.w);
        int blk = seg ^ (o & 7);
        *(uint4*)&smZ[o * 64 + blk * 8] = pk;
    }

    int lane = t & 63, wv = t >> 6;          // 8 waves
    int col = lane & 15, grp = lane >> 4;
    int w0 = wv * 32;

    short8b tf[2][2], bxf[2][2];
#pragma unroll
    for (int wt = 0; wt < 2; ++wt) {
        int w = w0 + wt * 16 + col;
#pragma unroll
        for (int kb = 0; kb < 2; ++kb) {
            tf[wt][kb] = *(const short8b*)&tbf[w * 64 + kb * 32 + grp * 8];
            int ch0 = kb * 32 + grp * 8;
            short8b v;
            if (BF16IN) {
                const unsigned short* xp = xinb + (size_t)(b * 64 + ch0) * 65536 + hh * 256 + w;
#pragma unroll
                for (int i = 0; i < 8; ++i) v[i] = (short)xp[(size_t)i * 65536];
            } else {
                const float* xp = xinf + (size_t)(b * 64 + ch0) * 65536 + hh * 256 + w;
#pragma unroll
                for (int i = 0; i < 8; ++i) v[i] = (short)f2bf(xp[(size_t)i * 65536]);
            }
            bxf[wt][kb] = v;
        }
    }
    __syncthreads();   // smZ ready

    unsigned short* xo = xout + (size_t)b * 4194304;   // 16 c-quads x 262144
    const unsigned short* WSp = wsk + l * 4096;
#pragma unroll
    for (int ot = 0; ot < 4; ++ot) {
        int o = ot * 16 + col;
        short8b az[2], ask[2];
#pragma unroll
        for (int kb = 0; kb < 2; ++kb) {
            int blk = (kb * 4 + grp) ^ (o & 7);
            az[kb] = *(const short8b*)&smZ[o * 64 + blk * 8];
            ask[kb] = *(const short8b*)&WSp[o * 64 + kb * 32 + grp * 8];
        }
        f32x4 bias = *(const f32x4*)&skip_b[l * 64 + ot * 16 + grp * 4];
#pragma unroll
        for (int wt = 0; wt < 2; ++wt) {
            f32x4 acc = bias;
            acc = __builtin_amdgcn_mfma_f32_16x16x32_bf16(az[0], tf[wt][0], acc, 0, 0, 0);
            acc = __builtin_amdgcn_mfma_f32_16x16x32_bf16(az[1], tf[wt][1], acc, 0, 0, 0);
            acc = __builtin_amdgcn_mfma_f32_16x16x32_bf16(ask[0], bxf[wt][0], acc, 0, 0, 0);
            acc = __builtin_amdgcn_mfma_f32_16x16x32_bf16(ask[1], bxf[wt][1], acc, 0, 0, 0);
            uint2 pk;
            pk.x = cvtpk(gelu_f(acc[0]), gelu_f(acc[1]));
            pk.y = cvtpk(gelu_f(acc[2]), gelu_f(acc[3]));
            int obase = ot * 16 + grp * 4;
            int px = hh * 256 + w0 + wt * 16 + col;
            *(uint2*)&xo[(size_t)(obase >> 2) * 262144 + px * 4] = pk;
        }
    }
}

// ---- MFMA channel MLP; input interleave-4. Weights LDS-staged (40 KB, swizzled).
// 512 threads, 8 waves x 16 px. OUT4=0: planar out; OUT4=1: interleave-4 out.
template<int OUT4>
__global__ __launch_bounds__(512) void k_mlp(const unsigned short* __restrict__ xin,
                                             const unsigned short* __restrict__ wb,
                                             const float* __restrict__ b1,
                                             const float* __restrict__ b2,
                                             const float* __restrict__ bsk,
                                             unsigned short* __restrict__ xout, int l) {
    __shared__ __align__(16) unsigned short smemH[128 * 128];   // 32 KB
    __shared__ __align__(16) unsigned short smW1[8192];         // 16 KB [n=128][8 oct swz]
    __shared__ __align__(16) unsigned short smW2[8192];         // 16 KB [o=64][16 oct swz]
    __shared__ __align__(16) unsigned short smWS[4096];         // 8 KB  [o=64][8 oct swz]
    int t = threadIdx.x;
    int b = blockIdx.y;
    int p0 = blockIdx.x * 128;

    const unsigned short* W1p = wb + l * 8192;
    const unsigned short* W2p = wb + 16384 + l * 8192;
    const unsigned short* WSp = wb + 32768 + l * 4096;
#pragma unroll
    for (int pass = 0; pass < 2; ++pass) {
        int g = pass * 512 + t;               // W1: 1024 octets
        int row = g >> 3, oct = g & 7;
        *(uint4*)&smW1[row * 64 + ((oct ^ (row & 7)) * 8)] = *(const uint4*)&W1p[g * 8];
    }
#pragma unroll
    for (int pass = 0; pass < 2; ++pass) {
        int g = pass * 512 + t;               // W2: 1024 octets
        int row = g >> 4, oct = g & 15;
        *(uint4*)&smW2[row * 128 + ((oct ^ (row & 7)) * 8)] = *(const uint4*)&W2p[g * 8];
    }
    if (t < 512) {                            // WS: 512 octets
        int g = t;
        int row = g >> 3, oct = g & 7;
        *(uint4*)&smWS[row * 64 + ((oct ^ (row & 7)) * 8)] = *(const uint4*)&WSp[g * 8];
    }

    int lane = t & 63, wv = t >> 6;          // 8 waves, 16 px each
    int col = lane & 15, grp = lane >> 4;
    int pxl = wv * 16 + col;                 // wave-private smemH row (0..127)
    int px = p0 + pxl;

    const unsigned short* xi = xin + (size_t)b * 4194304;
    short8b bx[2];
#pragma unroll
    for (int kb = 0; kb < 2; ++kb)
        bx[kb] = ld_frag_i4(xi, kb * 32 + grp * 8, px);
    __syncthreads();   // weights staged

#pragma unroll
    for (int ot = 0; ot < 8; ++ot) {
        int n1 = ot * 16 + col;
        short8b a0 = *(const short8b*)&smW1[n1 * 64 + ((grp ^ (n1 & 7)) * 8)];
        short8b a1 = *(const short8b*)&smW1[n1 * 64 + (((4 + grp) ^ (n1 & 7)) * 8)];
        int hm0 = ot * 16 + grp * 4;
        f32x4 acc = *(const f32x4*)&b1[l * 128 + hm0];
        acc = __builtin_amdgcn_mfma_f32_16x16x32_bf16(a0, bx[0], acc, 0, 0, 0);
        acc = __builtin_amdgcn_mfma_f32_16x16x32_bf16(a1, bx[1], acc, 0, 0, 0);
        uint2 hp;
        hp.x = cvtpk(gelu_f(acc[0]), gelu_f(acc[1]));
        hp.y = cvtpk(gelu_f(acc[2]), gelu_f(acc[3]));
        int blk = (hm0 >> 3) ^ (pxl & 7);
        *(uint2*)&smemH[pxl * 128 + blk * 8 + (hm0 & 7)] = hp;
    }

    short8b bh[4];
#pragma unroll
    for (int kb = 0; kb < 4; ++kb) {
        int blk = (kb * 4 + grp) ^ (pxl & 7);
        bh[kb] = *(const short8b*)&smemH[pxl * 128 + blk * 8];
    }

#pragma unroll
    for (int ot = 0; ot < 4; ++ot) {
        int o0 = ot * 16 + grp * 4;
        int n2 = ot * 16 + col;
        f32x4 acc = *(const f32x4*)&b2[l * 64 + o0];
        acc += *(const f32x4*)&bsk[l * 64 + o0];
        short8b a2[4], as[2];
#pragma unroll
        for (int kb = 0; kb < 4; ++kb)
            a2[kb] = *(const short8b*)&smW2[n2 * 128 + (((kb * 4 + grp) ^ (n2 & 7)) * 8)];
#pragma unroll
        for (int kb = 0; kb < 2; ++kb)
            as[kb] = *(const short8b*)&smWS[n2 * 64 + (((kb * 4 + grp) ^ (n2 & 7)) * 8)];
#pragma unroll
        for (int kb = 0; kb < 4; ++kb)
            acc = __builtin_amdgcn_mfma_f32_16x16x32_bf16(a2[kb], bh[kb], acc, 0, 0, 0);
#pragma unroll
        for (int kb = 0; kb < 2; ++kb)
            acc = __builtin_amdgcn_mfma_f32_16x16x32_bf16(as[kb], bx[kb], acc, 0, 0, 0);
        uint2 pk;
        pk.x = cvtpk(gelu_f(acc[0]), gelu_f(acc[1]));
        pk.y = cvtpk(gelu_f(acc[2]), gelu_f(acc[3]));
        if (OUT4) {
            unsigned short* xo = xout + (size_t)b * 4194304;
            *(uint2*)&xo[(size_t)(o0 >> 2) * 262144 + px * 4] = pk;
        } else {
            unsigned short* op = xout + (size_t)(b * 64 + o0) * 65536 + px;
            op[0]         = (unsigned short)(pk.x & 0xFFFF);
            op[65536]     = (unsigned short)(pk.x >> 16);
            op[2 * 65536] = (unsigned short)(pk.y & 0xFFFF);
            op[3 * 65536] = (unsigned short)(pk.y >> 16);
        }
    }
}

// ---- MFMA projection (interleave-4 bf16 input); PW1 LDS-staged.
// 512 threads, 8 waves x 16 px.
__global__ __launch_bounds__(512) void k_proj(const unsigned short* __restrict__ xin,
                                              const unsigned short* __restrict__ wb,
                                              const float* __restrict__ pb1,
                                              const float* __restrict__ pw2,
                                              const float* __restrict__ pb2,
                                              float* __restrict__ out) {
    __shared__ __align__(16) unsigned short smP1[16384];   // 32 KB [n=256][8 oct swz]
    int t = threadIdx.x;
    int b = blockIdx.y;
    int p0 = blockIdx.x * 128;

    const unsigned short* P1p = wb + 40960;
#pragma unroll
    for (int pass = 0; pass < 4; ++pass) {
        int g = pass * 512 + t;               // 2048 octets
        int row = g >> 3, oct = g & 7;
        *(uint4*)&smP1[row * 64 + ((oct ^ (row & 7)) * 8)] = *(const uint4*)&P1p[g * 8];
    }

    int lane = t & 63, wv = t >> 6;          // 8 waves, 16 px each
    int col = lane & 15, grp = lane >> 4;
    int px = p0 + wv * 16 + col;

    const unsigned short* xi = xin + (size_t)b * 4194304;
    short8b bx[2];
#pragma unroll
    for (int kb = 0; kb < 2; ++kb)
        bx[kb] = ld_frag_i4(xi, kb * 32 + grp * 8, px);
    __syncthreads();   // PW1 staged

    float psum = 0.f;
#pragma unroll
    for (int ot = 0; ot < 16; ++ot) {
        int n = ot * 16 + col;
        short8b a0 = *(const short8b*)&smP1[n * 64 + ((grp ^ (n & 7)) * 8)];
        short8b a1 = *(const short8b*)&smP1[n * 64 + (((4 + grp) ^ (n & 7)) * 8)];
        int o0 = ot * 16 + grp * 4;
        f32x4 b1v = *(const f32x4*)&pb1[o0];
        f32x4 w2v = *(const f32x4*)&pw2[o0];
        f32x4 acc = b1v;
        acc = __builtin_amdgcn_mfma_f32_16x16x32_bf16(a0, bx[0], acc, 0, 0, 0);
        acc = __builtin_amdgcn_mfma_f32_16x16x32_bf16(a1, bx[1], acc, 0, 0, 0);
        psum += w2v[0] * gelu_f(acc[0]) + w2v[1] * gelu_f(acc[1])
              + w2v[2] * gelu_f(acc[2]) + w2v[3] * gelu_f(acc[3]);
    }
    psum += __shfl_xor(psum, 16);
    psum += __shfl_xor(psum, 32);
    if (grp == 0)
        out[(size_t)b * 65536 + px] = psum + pb2[0];
}

extern "C" void kernel_launch(void* const* d_in, const int* in_sizes, int n_in,
                              void* d_out, int out_size, void* d_ws, size_t ws_size,
                              hipStream_t stream) {
    const float* x          = (const float*)d_in[0];
    const float2* sw1       = (const float2*)d_in[1];
    const float2* sw2       = (const float2*)d_in[2];
    const float* skip_w     = (const float*)d_in[3];
    const float* skip_b     = (const float*)d_in[4];
    const float* mlp_w1     = (const float*)d_in[5];
    const float* mlp_b1     = (const float*)d_in[6];
    const float* mlp_w2     = (const float*)d_in[7];
    const float* mlp_b2     = (const float*)d_in[8];
    const float* mlp_skip_w = (const float*)d_in[9];
    const float* mlp_skip_b = (const float*)d_in[10];
    const float* proj_w1    = (const float*)d_in[11];
    const float* proj_b1    = (const float*)d_in[12];
    const float* proj_w2    = (const float*)d_in[13];
    const float* proj_b2    = (const float*)d_in[14];

    float* ws = (float*)d_ws;
    unsigned short* XA4  = (unsigned short*)(ws + OFF_XA);             // interleave-4
    unsigned short* XBb  = (unsigned short*)(ws + OFF_XB);             // planar (layer-0 out)
    unsigned short* XB4  = (unsigned short*)(ws + OFF_XB) + 16777216;  // interleave-4 (layer-1 out)
    float* X1f = ws + OFF_Z1;
    float* Zre = ws + OFF_Z1;
    float* Zim = ws + OFF_Z1 + 2097152;
    float* XFre = ws + OFF_XF;
    float* XFim = ws + OFF_XF + 524288;
    float* OFT = ws + OFF_OF;
    const unsigned short* TBF = (const unsigned short*)(ws + OFF_TBF);
    const unsigned short* EH  = (const unsigned short*)(ws + OFF_EH);
    const unsigned short* EL  = (const unsigned short*)(ws + OFF_EL);
    const unsigned short* AFH = (const unsigned short*)(ws + OFF_AFH);
    const unsigned short* AFL = (const unsigned short*)(ws + OFF_AFL);
    const unsigned short* AIH = (const unsigned short*)(ws + OFF_AIH);
    const unsigned short* AIL = (const unsigned short*)(ws + OFF_AIL);
    unsigned short* WB = (unsigned short*)(ws + OFF_WBF);

    init_tw<<<640, 256, 0, stream>>>(ws);
    k_cvt<<<256, 256, 0, stream>>>(mlp_w1, mlp_w2, mlp_skip_w, proj_w1, skip_w, WB);

    // ---- layer 0 (fp32 input x) ----
    k_fwd_w_f32<<<1024, 256, 0, stream>>>(x, X1f, EH, EL);
    k_fwd_h<<<256, 256, 0, stream>>>(X1f, XFre, XFim, AFH, AFL);
    k_modemul<<<dim3(16, 64), 128, 0, stream>>>(XFre, XFim, sw1, sw2, OFT, 0);
    k_inv_h<<<256, 256, 0, stream>>>(OFT, Zre, Zim, AIH, AIL);
    k_invw_skip<0><<<dim3(256, 4), 512, 0, stream>>>(Zre, Zim, x, nullptr, TBF,
                                                     WB + 57344, skip_b, XA4, 0);
    k_mlp<0><<<dim3(512, 4), 512, 0, stream>>>(XA4, WB, mlp_b1, mlp_b2, mlp_skip_b, XBb, 0);

    // ---- layer 1 (planar XBb for DFT + skip) ----
    k_fwd_w_bf16<<<1024, 256, 0, stream>>>(XBb, X1f, EH, EL);
    k_fwd_h<<<256, 256, 0, stream>>>(X1f, XFre, XFim, AFH, AFL);
    k_modemul<<<dim3(16, 64), 128, 0, stream>>>(XFre, XFim, sw1, sw2, OFT, 1);
    k_inv_h<<<256, 256, 0, stream>>>(OFT, Zre, Zim, AIH, AIL);
    k_invw_skip<1><<<dim3(256, 4), 512, 0, stream>>>(Zre, Zim, nullptr, XBb, TBF,
                                                     WB + 57344, skip_b, XA4, 1);
    k_mlp<1><<<dim3(512, 4), 512, 0, stream>>>(XA4, WB, mlp_b1, mlp_b2, mlp_skip_b, XB4, 1);

    // ---- projection (interleave-4 input) ----
    k_proj<<<dim3(512, 4), 512, 0, stream>>>(XB4, WB, proj_b1, proj_w2, proj_b2,
                                             (float*)d_out);
}

// Round 25
// 286.076 us; speedup vs baseline: 1.0349x; 1.0349x over previous
//
#include <hip/hip_runtime.h>
#include <math.h>

// Problem constants: B=4, C=64, H=256, W=256, L=2, M1=M2=32, HM=128, P=256, O=1

// workspace layout (in floats)
#define OFF_XA   0                      // bf16 XA4: ushort[16777216], [c/4][px][4] interleave
#define OFF_XB   16777216               // bf16 XBb planar [16777216] + XB4 interleave [16777216]
#define OFF_Z1   33554432               // 4194304 floats: X1 (4M) OR Zre(2M)+Zim(2M)
#define OFF_XF   37748736               // XFre 524288 + XFim 524288
#define OFF_OF   38797312               // OFT 1048576  [plane][kx][2j+d]
#define OFF_TBF  39845888               // ushort[16384] invW twiddle Tt[w][k]
#define OFF_EH   39854080               // ushort[16384] fwdW E_hi[n][w]
#define OFF_EL   39862272               // ushort[16384] fwdW E_lo[n][w]
#define OFF_AFH  39870464               // ushort[65536] fwdH A_hi[n=128][k=512]
#define OFF_AFL  39903232               // ushort[65536] fwdH A_lo
#define OFF_AIH  39936000               // ushort[65536] invH A_hi[c=2][h=256][k=128]
#define OFF_AIL  39968768               // ushort[65536] invH A_lo
#define OFF_WBF  40001536               // ushort[65536] bf16 weights
// total = 40034304 floats ≈ 152.7 MiB

// WB (ushort) layout: [0:16384) mlp_w1 | [16384:32768) mlp_w2 | [32768:40960) mlp_skip_w
//                     [40960:57344) proj_w1 | [57344:65536) spectral skip_w (2x64x64)
// Interleave-4 activation layout: act[b*4194304 + (c>>2)*262144 + px*4 + (c&3)].

typedef __attribute__((ext_vector_type(8))) short short8b;   // 8 bf16 (4 VGPRs)
typedef __attribute__((ext_vector_type(4))) float f32x4;     // MFMA acc

// GELU via exp2-folded sigmoid form
__device__ __forceinline__ float gelu_f(float v) {
    float nu = v * fmaf(v * v, -0.10294345f, -2.3022078f);
    float e;
    asm("v_exp_f32 %0, %1" : "=v"(e) : "v"(nu));
    return v * __builtin_amdgcn_rcpf(1.0f + e);
}

__device__ __forceinline__ unsigned f2bf(float f) {
    unsigned int u = __float_as_uint(f);
    u += 0x7FFFu + ((u >> 16) & 1u);   // RNE
    return u >> 16;
}

// one-instruction convert+pack: lo16 = bf16(a), hi16 = bf16(b)
__device__ __forceinline__ unsigned cvtpk(float a, float b) {
    unsigned r;
    asm("v_cvt_pk_bf16_f32 %0, %1, %2" : "=v"(r) : "v"(a), "v"(b));
    return r;
}

// load an 8-channel frag from interleave-4 layout: 2x 8B loads
__device__ __forceinline__ short8b ld_frag_i4(const unsigned short* base, int ch0, int px) {
    const uint2* p0 = (const uint2*)(base + (size_t)(ch0 >> 2) * 262144 + px * 4);
    const uint2* p1 = (const uint2*)(base + (size_t)((ch0 >> 2) + 1) * 262144 + px * 4);
    uint2 lo = *p0, hi = *p1;
    uint4 pk = {lo.x, lo.y, hi.x, hi.y};
    return *(short8b*)&pk;
}

__global__ __launch_bounds__(256) void init_tw(float* ws) {
    int idx = blockIdx.x * 256 + threadIdx.x;
    unsigned short* tbf = (unsigned short*)(ws + OFF_TBF);
    unsigned short* eh  = (unsigned short*)(ws + OFF_EH);
    unsigned short* el  = (unsigned short*)(ws + OFF_EL);
    unsigned short* afh = (unsigned short*)(ws + OFF_AFH);
    unsigned short* afl = (unsigned short*)(ws + OFF_AFL);
    unsigned short* aih = (unsigned short*)(ws + OFF_AIH);
    unsigned short* ail = (unsigned short*)(ws + OFF_AIL);
    const double PI128 = 3.14159265358979323846 / 128.0;
    if (idx < 16384) {
        int w = idx >> 6, k = idx & 63;
        int kx = k >> 1;
        int m = (kx * w) & 255;
        double a = (double)m * PI128;
        float sc = (kx == 0) ? (1.0f / 65536.0f) : (2.0f / 65536.0f);
        float v = (k & 1) ? (float)(-sin(a)) * sc : (float)cos(a) * sc;
        tbf[idx] = (unsigned short)f2bf(v);
    }
    int i2 = idx - 16384;
    if (i2 >= 0 && i2 < 16384) {
        int n = i2 >> 8, w = i2 & 255;
        int kx = n >> 1;
        int m = (kx * w) & 255;
        double a = (double)m * PI128;
        float v = (n & 1) ? (float)(-sin(a)) : (float)cos(a);
        unsigned h = f2bf(v);
        eh[i2] = (unsigned short)h;
        el[i2] = (unsigned short)f2bf(v - __uint_as_float(h << 16));
    }
    int i3 = idx - 32768;
    if (i3 >= 0 && i3 < 65536) {
        int n = i3 >> 9, k = i3 & 511;
        int j = n & 63, c = n >> 6;
        int h = k >> 1, d = k & 1;
        int ky = (j < 32) ? j : (192 + j);
        int m = (ky * h) & 255;
        double a = (double)m * PI128;
        float cv = (float)cos(a), sv = (float)sin(a);
        float v = (c == 0) ? (d ? sv : cv) : (d ? cv : -sv);
        unsigned hh = f2bf(v);
        afh[i3] = (unsigned short)hh;
        afl[i3] = (unsigned short)f2bf(v - __uint_as_float(hh << 16));
    }
    int i4 = idx - 98304;
    if (i4 >= 0 && i4 < 65536) {
        int c = i4 >> 15, rem = i4 & 32767;
        int h = rem >> 7, k = rem & 127;
        int j = k >> 1, d = k & 1;
        int ky = (j < 32) ? j : (192 + j);
        int m = (ky * h) & 255;
        double a = (double)m * PI128;
        float cv = (float)cos(a), sv = (float)sin(a);
        float v = (c == 0) ? (d ? -sv : cv) : (d ? cv : sv);
        unsigned hh = f2bf(v);
        aih[i4] = (unsigned short)hh;
        ail[i4] = (unsigned short)f2bf(v - __uint_as_float(hh << 16));
    }
}

__global__ __launch_bounds__(256) void k_cvt(const float* __restrict__ w1,
                                             const float* __restrict__ w2,
                                             const float* __restrict__ wsk,
                                             const float* __restrict__ pw1,
                                             const float* __restrict__ ssk,
                                             unsigned short* __restrict__ wb) {
    int idx = blockIdx.x * 256 + threadIdx.x;
    if (idx < 16384)       wb[idx] = (unsigned short)f2bf(w1[idx]);
    else if (idx < 32768)  wb[idx] = (unsigned short)f2bf(w2[idx - 16384]);
    else if (idx < 40960)  wb[idx] = (unsigned short)f2bf(wsk[idx - 32768]);
    else if (idx < 57344)  wb[idx] = (unsigned short)f2bf(pw1[idx - 40960]);
    else if (idx < 65536)  wb[idx] = (unsigned short)f2bf(ssk[idx - 57344]);
}

// ---- MFMA fwd-W DFT, fp32 input (layer 0), split-bf16 3-pass.
// Twiddle tables LDS-staged (64 KB, XOR-swizzled).
__global__ __launch_bounds__(256) void k_fwd_w_f32(const float* __restrict__ x,
                                                   float* __restrict__ X1f,
                                                   const unsigned short* __restrict__ EH,
                                                   const unsigned short* __restrict__ EL) {
    __shared__ __align__(16) unsigned short smEH[16384];   // 32 KB [n][w-oct swizzled]
    __shared__ __align__(16) unsigned short smEL[16384];   // 32 KB
    int t = threadIdx.x;
#pragma unroll
    for (int pass = 0; pass < 8; ++pass) {
        int g = pass * 256 + t;               // 16B granule: row=g>>5, oct=g&31
        int rown = g >> 5, oct = g & 31;
        int dst = rown * 256 + ((oct ^ (rown & 7)) * 8);
        *(uint4*)&smEH[dst] = *(const uint4*)&EH[g * 8];
        *(uint4*)&smEL[dst] = *(const uint4*)&EL[g * 8];
    }
    __syncthreads();

    int lane = t & 63, wv = t >> 6;
    int col = lane & 15, grp = lane >> 4;
    size_t row0 = (size_t)blockIdx.x * 64;
    int row = wv * 16 + col;
    const float* rp = x + (row0 + row) * 256 + grp * 8;

    short8b bH[8], bL[8];
#pragma unroll
    for (int kb = 0; kb < 8; ++kb) {
        float4 v0 = *(const float4*)(rp + kb * 32);
        float4 v1 = *(const float4*)(rp + kb * 32 + 4);
        float vv[8] = {v0.x, v0.y, v0.z, v0.w, v1.x, v1.y, v1.z, v1.w};
        short8b vH, vL;
#pragma unroll
        for (int i = 0; i < 8; ++i) {
            unsigned h = f2bf(vv[i]);
            vH[i] = (short)h;
            vL[i] = (short)f2bf(vv[i] - __uint_as_float(h << 16));
        }
        bH[kb] = vH; bL[kb] = vL;
    }
#pragma unroll
    for (int ot = 0; ot < 4; ++ot) {
        int n = ot * 16 + col;
        const unsigned short* eh = &smEH[n * 256];
        const unsigned short* el = &smEL[n * 256];
        f32x4 acc = {0.f, 0.f, 0.f, 0.f};
#pragma unroll
        for (int kb = 0; kb < 8; ++kb) {
            int off = ((kb * 4 + grp) ^ (n & 7)) * 8;
            const short8b aH = *(const short8b*)&eh[off];
            const short8b aL = *(const short8b*)&el[off];
            acc = __builtin_amdgcn_mfma_f32_16x16x32_bf16(aH, bH[kb], acc, 0, 0, 0);
            acc = __builtin_amdgcn_mfma_f32_16x16x32_bf16(aH, bL[kb], acc, 0, 0, 0);
            acc = __builtin_amdgcn_mfma_f32_16x16x32_bf16(aL, bH[kb], acc, 0, 0, 0);
        }
        *(float4*)&X1f[(row0 + row) * 64 + ot * 16 + grp * 4] = *(float4*)&acc;
    }
}

// ---- MFMA fwd-W DFT, bf16 input (layer 1): same LDS-staged twiddles.
__global__ __launch_bounds__(256) void k_fwd_w_bf16(const unsigned short* __restrict__ xb,
                                                    float* __restrict__ X1f,
                                                    const unsigned short* __restrict__ EH,
                                                    const unsigned short* __restrict__ EL) {
    __shared__ __align__(16) unsigned short smEH[16384];
    __shared__ __align__(16) unsigned short smEL[16384];
    int t = threadIdx.x;
#pragma unroll
    for (int pass = 0; pass < 8; ++pass) {
        int g = pass * 256 + t;
        int rown = g >> 5, oct = g & 31;
        int dst = rown * 256 + ((oct ^ (rown & 7)) * 8);
        *(uint4*)&smEH[dst] = *(const uint4*)&EH[g * 8];
        *(uint4*)&smEL[dst] = *(const uint4*)&EL[g * 8];
    }
    __syncthreads();

    int lane = t & 63, wv = t >> 6;
    int col = lane & 15, grp = lane >> 4;
    size_t row0 = (size_t)blockIdx.x * 64;
    int row = wv * 16 + col;
    const unsigned short* rp = xb + (row0 + row) * 256 + grp * 8;

    short8b bH[8];
#pragma unroll
    for (int kb = 0; kb < 8; ++kb)
        bH[kb] = *(const short8b*)(rp + kb * 32);
#pragma unroll
    for (int ot = 0; ot < 4; ++ot) {
        int n = ot * 16 + col;
        const unsigned short* eh = &smEH[n * 256];
        const unsigned short* el = &smEL[n * 256];
        f32x4 acc = {0.f, 0.f, 0.f, 0.f};
#pragma unroll
        for (int kb = 0; kb < 8; ++kb) {
            int off = ((kb * 4 + grp) ^ (n & 7)) * 8;
            const short8b aH = *(const short8b*)&eh[off];
            const short8b aL = *(const short8b*)&el[off];
            acc = __builtin_amdgcn_mfma_f32_16x16x32_bf16(aH, bH[kb], acc, 0, 0, 0);
            acc = __builtin_amdgcn_mfma_f32_16x16x32_bf16(aL, bH[kb], acc, 0, 0, 0);
        }
        *(float4*)&X1f[(row0 + row) * 64 + ot * 16 + grp * 4] = *(float4*)&acc;
    }
}

// ---- MFMA forward DFT over H, 2-pass (B=X1 as bf16; twiddle A keeps hi+lo)
__global__ __launch_bounds__(256) void k_fwd_h(const float* __restrict__ X1f,
                                               float* __restrict__ XFre,
                                               float* __restrict__ XFim,
                                               const unsigned short* __restrict__ AFH,
                                               const unsigned short* __restrict__ AFL) {
    __shared__ __align__(16) unsigned short smH[32 * 512];   // 32 KB
    int t = threadIdx.x;
    int plane = blockIdx.x;
    const float* xp = X1f + (size_t)plane * 16384;
#pragma unroll
    for (int pass = 0; pass < 16; ++pass) {
        int idx = pass * 256 + t;
        int h = idx >> 4, seg = idx & 15;
        float4 v = *(const float4*)(xp + h * 64 + seg * 4);
        int kx0 = seg * 2, kx1 = seg * 2 + 1;
        int k0 = 2 * h;
        int oct = k0 >> 3, e = k0 & 7;
        int b0 = oct ^ (kx0 & 7), b1 = oct ^ (kx1 & 7);
        *(unsigned*)&smH[kx0 * 512 + b0 * 8 + e] = cvtpk(v.x, v.y);
        *(unsigned*)&smH[kx1 * 512 + b1 * 8 + e] = cvtpk(v.z, v.w);
    }
    __syncthreads();
    int lane = t & 63, wv = t >> 6;
    int col = lane & 15, grp = lane >> 4;
#pragma unroll
    for (int mi = 0; mi < 2; ++mi) {
        int mt = wv * 2 + mi;
        const unsigned short* Ah = AFH + (mt * 16 + col) * 512;
        const unsigned short* Al = AFL + (mt * 16 + col) * 512;
        f32x4 acc0 = {0.f, 0.f, 0.f, 0.f}, acc1 = {0.f, 0.f, 0.f, 0.f};
#pragma unroll
        for (int kb = 0; kb < 16; ++kb) {
            short8b aH = *(const short8b*)&Ah[kb * 32 + grp * 8];
            short8b aL = *(const short8b*)&Al[kb * 32 + grp * 8];
#pragma unroll
            for (int nt = 0; nt < 2; ++nt) {
                int kx = nt * 16 + col;
                int blk = (kb * 4 + grp) ^ (kx & 7);
                short8b bH = *(const short8b*)&smH[kx * 512 + blk * 8];
                f32x4 a = (nt == 0) ? acc0 : acc1;
                a = __builtin_amdgcn_mfma_f32_16x16x32_bf16(aH, bH, a, 0, 0, 0);
                a = __builtin_amdgcn_mfma_f32_16x16x32_bf16(aL, bH, a, 0, 0, 0);
                if (nt == 0) acc0 = a; else acc1 = a;
            }
        }
#pragma unroll
        for (int nt = 0; nt < 2; ++nt) {
            int kx = nt * 16 + col;
            f32x4 a = (nt == 0) ? acc0 : acc1;
#pragma unroll
            for (int r = 0; r < 4; ++r) {
                int n = mt * 16 + grp * 4 + r;
                float* dst = (n < 64)
                    ? (XFre + (size_t)plane * 2048 + n * 32 + kx)
                    : (XFim + (size_t)plane * 2048 + (n - 64) * 32 + kx);
                *dst = a[r];
            }
        }
    }
}

// ---- per-mode complex matmul: 4 o's per thread, i-reduction split 4-way.
// 512 threads = (ih 4) x (b 4) x (kx 32); 8 waves/block, grid 16x64 -> 32 waves/CU.
__global__ __launch_bounds__(512) void k_modemul(const float* __restrict__ XFre,
                                                 const float* __restrict__ XFim,
                                                 const float2* __restrict__ sw1,
                                                 const float2* __restrict__ sw2,
                                                 float* __restrict__ OFT, int l) {
    __shared__ float red[4][8][128];   // [ih][q*2+d][b*32+kx] = 16 KB
    int o0 = blockIdx.x * 4, j = blockIdx.y;
    int tid = threadIdx.x;
    int kx = tid & 31, b = (tid >> 5) & 3, ih = tid >> 7;
    int jj = (j < 32) ? j : (j - 32);
    const float2* W0 = ((j < 32) ? sw1 : sw2)
                     + (l * 4194304 + (size_t)o0 * 1024 + jj * 32 + kx);
    const float* Xr = XFre + (size_t)(b * 64) * 2048 + j * 32 + kx;
    const float* Xi = XFim + (size_t)(b * 64) * 2048 + j * 32 + kx;
    float ar[4] = {0.f, 0.f, 0.f, 0.f}, ai[4] = {0.f, 0.f, 0.f, 0.f};
    int i0 = ih * 16;
#pragma unroll 4
    for (int ii = 0; ii < 16; ++ii) {
        int i = i0 + ii;
        float xr = Xr[(size_t)i * 2048], xi = Xi[(size_t)i * 2048];
        const float2* Wi = W0 + (size_t)i * 65536;
#pragma unroll
        for (int q = 0; q < 4; ++q) {
            float2 w = Wi[q * 1024];
            ar[q] += xr * w.x - xi * w.y;
            ai[q] += xr * w.y + xi * w.x;
        }
    }
    int bk = b * 32 + kx;
#pragma unroll
    for (int q = 0; q < 4; ++q) {
        red[ih][q * 2 + 0][bk] = ar[q];
        red[ih][q * 2 + 1][bk] = ai[q];
    }
    __syncthreads();
    if (ih == 0) {
#pragma unroll
        for (int q = 0; q < 4; ++q) {
            float sr = red[0][q * 2][bk] + red[1][q * 2][bk]
                     + red[2][q * 2][bk] + red[3][q * 2][bk];
            float si = red[0][q * 2 + 1][bk] + red[1][q * 2 + 1][bk]
                     + red[2][q * 2 + 1][bk] + red[3][q * 2 + 1][bk];
            float* d = OFT + (size_t)(b * 64 + o0 + q) * 4096 + kx * 128 + 2 * j;
            d[0] = sr;
            d[1] = si;
        }
    }
}

// ---- MFMA inverse DFT over H, 2-pass
__global__ __launch_bounds__(256) void k_inv_h(const float* __restrict__ OFT,
                                               float* __restrict__ Zre,
                                               float* __restrict__ Zim,
                                               const unsigned short* __restrict__ AIH,
                                               const unsigned short* __restrict__ AIL) {
    __shared__ __align__(16) unsigned short smH[32 * 128];   // 8 KB
    int t = threadIdx.x;
    int plane = blockIdx.x;
    const float* op = OFT + (size_t)plane * 4096;
#pragma unroll
    for (int pass = 0; pass < 4; ++pass) {
        int idx = pass * 256 + t;
        int kx = idx >> 5, seg = idx & 31;
        float4 v = *(const float4*)(op + kx * 128 + seg * 4);
        int k0 = seg * 4;
        int oct = k0 >> 3, e = k0 & 7;
        int blk = oct ^ (kx & 7);
        uint2 ph = {cvtpk(v.x, v.y), cvtpk(v.z, v.w)};
        *(uint2*)&smH[kx * 128 + blk * 8 + e] = ph;
    }
    __syncthreads();
    int lane = t & 63, wv = t >> 6;
    int col = lane & 15, grp = lane >> 4;
#pragma unroll
    for (int mi = 0; mi < 4; ++mi) {
        int mt = wv * 4 + mi;
#pragma unroll
        for (int cc = 0; cc < 2; ++cc) {
            const unsigned short* Ah = AIH + cc * 32768 + (mt * 16 + col) * 128;
            const unsigned short* Al = AIL + cc * 32768 + (mt * 16 + col) * 128;
            f32x4 acc0 = {0.f, 0.f, 0.f, 0.f}, acc1 = {0.f, 0.f, 0.f, 0.f};
#pragma unroll
            for (int kb = 0; kb < 4; ++kb) {
                short8b aH = *(const short8b*)&Ah[kb * 32 + grp * 8];
                short8b aL = *(const short8b*)&Al[kb * 32 + grp * 8];
#pragma unroll
                for (int nt = 0; nt < 2; ++nt) {
                    int kx = nt * 16 + col;
                    int blk = (kb * 4 + grp) ^ (kx & 7);
                    short8b bH = *(const short8b*)&smH[kx * 128 + blk * 8];
                    f32x4 a = (nt == 0) ? acc0 : acc1;
                    a = __builtin_amdgcn_mfma_f32_16x16x32_bf16(aH, bH, a, 0, 0, 0);
                    a = __builtin_amdgcn_mfma_f32_16x16x32_bf16(aL, bH, a, 0, 0, 0);
                    if (nt == 0) acc0 = a; else acc1 = a;
                }
            }
            float* Zc = (cc == 0) ? Zre : Zim;
#pragma unroll
            for (int nt = 0; nt < 2; ++nt) {
                int kx = nt * 16 + col;
                f32x4 a = (nt == 0) ? acc0 : acc1;
#pragma unroll
                for (int r = 0; r < 4; ++r) {
                    int h = mt * 16 + grp * 4 + r;
                    Zc[(size_t)plane * 8192 + h * 32 + kx] = a[r];
                }
            }
        }
    }
}

// ---- MFMA fused inverse-W DFT + channel skip + bias + GELU -> XA interleave-4
template<int BF16IN>
__global__ __launch_bounds__(512) void k_invw_skip(const float* __restrict__ Zre,
                                                   const float* __restrict__ Zim,
                                                   const float* __restrict__ xinf,
                                                   const unsigned short* __restrict__ xinb,
                                                   const unsigned short* __restrict__ tbf,
                                                   const unsigned short* __restrict__ wsk,
                                                   const float* __restrict__ skip_b,
                                                   unsigned short* __restrict__ xout, int l) {
    __shared__ __align__(16) unsigned short smZ[64 * 64];    // 8 KB, reused by 8 waves
    int t = threadIdx.x;
    int hh = blockIdx.x, b = blockIdx.y;

    {
        int o = t >> 3, seg = t & 7;
        const float* zr = Zre + (size_t)(b * 64 + o) * 8192 + hh * 32 + seg * 4;
        const float* zi = Zim + (size_t)(b * 64 + o) * 8192 + hh * 32 + seg * 4;
        float4 r = *(const float4*)zr;
        float4 i = *(const float4*)zi;
        uint4 pk;
        pk.x = cvtpk(r.x, i.x);
        pk.y = cvtpk(r.y, i.y);
        pk.z = cvtpk(r.z, i.z);
        pk.w = cvtpk(r.w, i.w);
        int blk = seg ^ (o & 7);
        *(uint4*)&smZ[o * 64 + blk * 8] = pk;
    }

    int lane = t & 63, wv = t >> 6;          // 8 waves
    int col = lane & 15, grp = lane >> 4;
    int w0 = wv * 32;

    short8b tf[2][2], bxf[2][2];
#pragma unroll
    for (int wt = 0; wt < 2; ++wt) {
        int w = w0 + wt * 16 + col;
#pragma unroll
        for (int kb = 0; kb < 2; ++kb) {
            tf[wt][kb] = *(const short8b*)&tbf[w * 64 + kb * 32 + grp * 8];
            int ch0 = kb * 32 + grp * 8;
            short8b v;
            if (BF16IN) {
                const unsigned short* xp = xinb + (size_t)(b * 64 + ch0) * 65536 + hh * 256 + w;
#pragma unroll
                for (int i = 0; i < 8; ++i) v[i] = (short)xp[(size_t)i * 65536];
            } else {
                const float* xp = xinf + (size_t)(b * 64 + ch0) * 65536 + hh * 256 + w;
#pragma unroll
                for (int i = 0; i < 8; ++i) v[i] = (short)f2bf(xp[(size_t)i * 65536]);
            }
            bxf[wt][kb] = v;
        }
    }
    __syncthreads();   // smZ ready

    unsigned short* xo = xout + (size_t)b * 4194304;   // 16 c-quads x 262144
    const unsigned short* WSp = wsk + l * 4096;
#pragma unroll
    for (int ot = 0; ot < 4; ++ot) {
        int o = ot * 16 + col;
        short8b az[2], ask[2];
#pragma unroll
        for (int kb = 0; kb < 2; ++kb) {
            int blk = (kb * 4 + grp) ^ (o & 7);
            az[kb] = *(const short8b*)&smZ[o * 64 + blk * 8];
            ask[kb] = *(const short8b*)&WSp[o * 64 + kb * 32 + grp * 8];
        }
        f32x4 bias = *(const f32x4*)&skip_b[l * 64 + ot * 16 + grp * 4];
#pragma unroll
        for (int wt = 0; wt < 2; ++wt) {
            f32x4 acc = bias;
            acc = __builtin_amdgcn_mfma_f32_16x16x32_bf16(az[0], tf[wt][0], acc, 0, 0, 0);
            acc = __builtin_amdgcn_mfma_f32_16x16x32_bf16(az[1], tf[wt][1], acc, 0, 0, 0);
            acc = __builtin_amdgcn_mfma_f32_16x16x32_bf16(ask[0], bxf[wt][0], acc, 0, 0, 0);
            acc = __builtin_amdgcn_mfma_f32_16x16x32_bf16(ask[1], bxf[wt][1], acc, 0, 0, 0);
            uint2 pk;
            pk.x = cvtpk(gelu_f(acc[0]), gelu_f(acc[1]));
            pk.y = cvtpk(gelu_f(acc[2]), gelu_f(acc[3]));
            int obase = ot * 16 + grp * 4;
            int px = hh * 256 + w0 + wt * 16 + col;
            *(uint2*)&xo[(size_t)(obase >> 2) * 262144 + px * 4] = pk;
        }
    }
}

// ---- MFMA channel MLP; input interleave-4. Weights LDS-staged (40 KB, swizzled).
// 512 threads, 8 waves x 16 px. OUT4=0: planar out; OUT4=1: interleave-4 out.
template<int OUT4>
__global__ __launch_bounds__(512) void k_mlp(const unsigned short* __restrict__ xin,
                                             const unsigned short* __restrict__ wb,
                                             const float* __restrict__ b1,
                                             const float* __restrict__ b2,
                                             const float* __restrict__ bsk,
                                             unsigned short* __restrict__ xout, int l) {
    __shared__ __align__(16) unsigned short smemH[128 * 128];   // 32 KB
    __shared__ __align__(16) unsigned short smW1[8192];         // 16 KB [n=128][8 oct swz]
    __shared__ __align__(16) unsigned short smW2[8192];         // 16 KB [o=64][16 oct swz]
    __shared__ __align__(16) unsigned short smWS[4096];         // 8 KB  [o=64][8 oct swz]
    int t = threadIdx.x;
    int b = blockIdx.y;
    int p0 = blockIdx.x * 128;

    const unsigned short* W1p = wb + l * 8192;
    const unsigned short* W2p = wb + 16384 + l * 8192;
    const unsigned short* WSp = wb + 32768 + l * 4096;
#pragma unroll
    for (int pass = 0; pass < 2; ++pass) {
        int g = pass * 512 + t;               // W1: 1024 octets
        int row = g >> 3, oct = g & 7;
        *(uint4*)&smW1[row * 64 + ((oct ^ (row & 7)) * 8)] = *(const uint4*)&W1p[g * 8];
    }
#pragma unroll
    for (int pass = 0; pass < 2; ++pass) {
        int g = pass * 512 + t;               // W2: 1024 octets
        int row = g >> 4, oct = g & 15;
        *(uint4*)&smW2[row * 128 + ((oct ^ (row & 7)) * 8)] = *(const uint4*)&W2p[g * 8];
    }
    if (t < 512) {                            // WS: 512 octets
        int g = t;
        int row = g >> 3, oct = g & 7;
        *(uint4*)&smWS[row * 64 + ((oct ^ (row & 7)) * 8)] = *(const uint4*)&WSp[g * 8];
    }

    int lane = t & 63, wv = t >> 6;          // 8 waves, 16 px each
    int col = lane & 15, grp = lane >> 4;
    int pxl = wv * 16 + col;                 // wave-private smemH row (0..127)
    int px = p0 + pxl;

    const unsigned short* xi = xin + (size_t)b * 4194304;
    short8b bx[2];
#pragma unroll
    for (int kb = 0; kb < 2; ++kb)
        bx[kb] = ld_frag_i4(xi, kb * 32 + grp * 8, px);
    __syncthreads();   // weights staged

#pragma unroll
    for (int ot = 0; ot < 8; ++ot) {
        int n1 = ot * 16 + col;
        short8b a0 = *(const short8b*)&smW1[n1 * 64 + ((grp ^ (n1 & 7)) * 8)];
        short8b a1 = *(const short8b*)&smW1[n1 * 64 + (((4 + grp) ^ (n1 & 7)) * 8)];
        int hm0 = ot * 16 + grp * 4;
        f32x4 acc = *(const f32x4*)&b1[l * 128 + hm0];
        acc = __builtin_amdgcn_mfma_f32_16x16x32_bf16(a0, bx[0], acc, 0, 0, 0);
        acc = __builtin_amdgcn_mfma_f32_16x16x32_bf16(a1, bx[1], acc, 0, 0, 0);
        uint2 hp;
        hp.x = cvtpk(gelu_f(acc[0]), gelu_f(acc[1]));
        hp.y = cvtpk(gelu_f(acc[2]), gelu_f(acc[3]));
        int blk = (hm0 >> 3) ^ (pxl & 7);
        *(uint2*)&smemH[pxl * 128 + blk * 8 + (hm0 & 7)] = hp;
    }

    short8b bh[4];
#pragma unroll
    for (int kb = 0; kb < 4; ++kb) {
        int blk = (kb * 4 + grp) ^ (pxl & 7);
        bh[kb] = *(const short8b*)&smemH[pxl * 128 + blk * 8];
    }

#pragma unroll
    for (int ot = 0; ot < 4; ++ot) {
        int o0 = ot * 16 + grp * 4;
        int n2 = ot * 16 + col;
        f32x4 acc = *(const f32x4*)&b2[l * 64 + o0];
        acc += *(const f32x4*)&bsk[l * 64 + o0];
        short8b a2[4], as[2];
#pragma unroll
        for (int kb = 0; kb < 4; ++kb)
            a2[kb] = *(const short8b*)&smW2[n2 * 128 + (((kb * 4 + grp) ^ (n2 & 7)) * 8)];
#pragma unroll
        for (int kb = 0; kb < 2; ++kb)
            as[kb] = *(const short8b*)&smWS[n2 * 64 + (((kb * 4 + grp) ^ (n2 & 7)) * 8)];
#pragma unroll
        for (int kb = 0; kb < 4; ++kb)
            acc = __builtin_amdgcn_mfma_f32_16x16x32_bf16(a2[kb], bh[kb], acc, 0, 0, 0);
#pragma unroll
        for (int kb = 0; kb < 2; ++kb)
            acc = __builtin_amdgcn_mfma_f32_16x16x32_bf16(as[kb], bx[kb], acc, 0, 0, 0);
        uint2 pk;
        pk.x = cvtpk(gelu_f(acc[0]), gelu_f(acc[1]));
        pk.y = cvtpk(gelu_f(acc[2]), gelu_f(acc[3]));
        if (OUT4) {
            unsigned short* xo = xout + (size_t)b * 4194304;
            *(uint2*)&xo[(size_t)(o0 >> 2) * 262144 + px * 4] = pk;
        } else {
            unsigned short* op = xout + (size_t)(b * 64 + o0) * 65536 + px;
            op[0]         = (unsigned short)(pk.x & 0xFFFF);
            op[65536]     = (unsigned short)(pk.x >> 16);
            op[2 * 65536] = (unsigned short)(pk.y & 0xFFFF);
            op[3 * 65536] = (unsigned short)(pk.y >> 16);
        }
    }
}

// ---- MFMA projection (interleave-4 bf16 input); PW1 LDS-staged.
// 512 threads, 8 waves x 16 px.
__global__ __launch_bounds__(512) void k_proj(const unsigned short* __restrict__ xin,
                                              const unsigned short* __restrict__ wb,
                                              const float* __restrict__ pb1,
                                              const float* __restrict__ pw2,
                                              const float* __restrict__ pb2,
                                              float* __restrict__ out) {
    __shared__ __align__(16) unsigned short smP1[16384];   // 32 KB [n=256][8 oct swz]
    int t = threadIdx.x;
    int b = blockIdx.y;
    int p0 = blockIdx.x * 128;

    const unsigned short* P1p = wb + 40960;
#pragma unroll
    for (int pass = 0; pass < 4; ++pass) {
        int g = pass * 512 + t;               // 2048 octets
        int row = g >> 3, oct = g & 7;
        *(uint4*)&smP1[row * 64 + ((oct ^ (row & 7)) * 8)] = *(const uint4*)&P1p[g * 8];
    }

    int lane = t & 63, wv = t >> 6;          // 8 waves, 16 px each
    int col = lane & 15, grp = lane >> 4;
    int px = p0 + wv * 16 + col;

    const unsigned short* xi = xin + (size_t)b * 4194304;
    short8b bx[2];
#pragma unroll
    for (int kb = 0; kb < 2; ++kb)
        bx[kb] = ld_frag_i4(xi, kb * 32 + grp * 8, px);
    __syncthreads();   // PW1 staged

    float psum = 0.f;
#pragma unroll
    for (int ot = 0; ot < 16; ++ot) {
        int n = ot * 16 + col;
        short8b a0 = *(const short8b*)&smP1[n * 64 + ((grp ^ (n & 7)) * 8)];
        short8b a1 = *(const short8b*)&smP1[n * 64 + (((4 + grp) ^ (n & 7)) * 8)];
        int o0 = ot * 16 + grp * 4;
        f32x4 b1v = *(const f32x4*)&pb1[o0];
        f32x4 w2v = *(const f32x4*)&pw2[o0];
        f32x4 acc = b1v;
        acc = __builtin_amdgcn_mfma_f32_16x16x32_bf16(a0, bx[0], acc, 0, 0, 0);
        acc = __builtin_amdgcn_mfma_f32_16x16x32_bf16(a1, bx[1], acc, 0, 0, 0);
        psum += w2v[0] * gelu_f(acc[0]) + w2v[1] * gelu_f(acc[1])
              + w2v[2] * gelu_f(acc[2]) + w2v[3] * gelu_f(acc[3]);
    }
    psum += __shfl_xor(psum, 16);
    psum += __shfl_xor(psum, 32);
    if (grp == 0)
        out[(size_t)b * 65536 + px] = psum + pb2[0];
}

extern "C" void kernel_launch(void* const* d_in, const int* in_sizes, int n_in,
                              void* d_out, int out_size, void* d_ws, size_t ws_size,
                              hipStream_t stream) {
    const float* x          = (const float*)d_in[0];
    const float2* sw1       = (const float2*)d_in[1];
    const float2* sw2       = (const float2*)d_in[2];
    const float* skip_w     = (const float*)d_in[3];
    const float* skip_b     = (const float*)d_in[4];
    const float* mlp_w1     = (const float*)d_in[5];
    const float* mlp_b1     = (const float*)d_in[6];
    const float* mlp_w2     = (const float*)d_in[7];
    const float* mlp_b2     = (const float*)d_in[8];
    const float* mlp_skip_w = (const float*)d_in[9];
    const float* mlp_skip_b = (const float*)d_in[10];
    const float* proj_w1    = (const float*)d_in[11];
    const float* proj_b1    = (const float*)d_in[12];
    const float* proj_w2    = (const float*)d_in[13];
    const float* proj_b2    = (const float*)d_in[14];

    float* ws = (float*)d_ws;
    unsigned short* XA4  = (unsigned short*)(ws + OFF_XA);             // interleave-4
    unsigned short* XBb  = (unsigned short*)(ws + OFF_XB);             // planar (layer-0 out)
    unsigned short* XB4  = (unsigned short*)(ws + OFF_XB) + 16777216;  // interleave-4 (layer-1 out)
    float* X1f = ws + OFF_Z1;
    float* Zre = ws + OFF_Z1;
    float* Zim = ws + OFF_Z1 + 2097152;
    float* XFre = ws + OFF_XF;
    float* XFim = ws + OFF_XF + 524288;
    float* OFT = ws + OFF_OF;
    const unsigned short* TBF = (const unsigned short*)(ws + OFF_TBF);
    const unsigned short* EH  = (const unsigned short*)(ws + OFF_EH);
    const unsigned short* EL  = (const unsigned short*)(ws + OFF_EL);
    const unsigned short* AFH = (const unsigned short*)(ws + OFF_AFH);
    const unsigned short* AFL = (const unsigned short*)(ws + OFF_AFL);
    const unsigned short* AIH = (const unsigned short*)(ws + OFF_AIH);
    const unsigned short* AIL = (const unsigned short*)(ws + OFF_AIL);
    unsigned short* WB = (unsigned short*)(ws + OFF_WBF);

    init_tw<<<640, 256, 0, stream>>>(ws);
    k_cvt<<<256, 256, 0, stream>>>(mlp_w1, mlp_w2, mlp_skip_w, proj_w1, skip_w, WB);

    // ---- layer 0 (fp32 input x) ----
    k_fwd_w_f32<<<1024, 256, 0, stream>>>(x, X1f, EH, EL);
    k_fwd_h<<<256, 256, 0, stream>>>(X1f, XFre, XFim, AFH, AFL);
    k_modemul<<<dim3(16, 64), 512, 0, stream>>>(XFre, XFim, sw1, sw2, OFT, 0);
    k_inv_h<<<256, 256, 0, stream>>>(OFT, Zre, Zim, AIH, AIL);
    k_invw_skip<0><<<dim3(256, 4), 512, 0, stream>>>(Zre, Zim, x, nullptr, TBF,
                                                     WB + 57344, skip_b, XA4, 0);
    k_mlp<0><<<dim3(512, 4), 512, 0, stream>>>(XA4, WB, mlp_b1, mlp_b2, mlp_skip_b, XBb, 0);

    // ---- layer 1 (planar XBb for DFT + skip) ----
    k_fwd_w_bf16<<<1024, 256, 0, stream>>>(XBb, X1f, EH, EL);
    k_fwd_h<<<256, 256, 0, stream>>>(X1f, XFre, XFim, AFH, AFL);
    k_modemul<<<dim3(16, 64), 512, 0, stream>>>(XFre, XFim, sw1, sw2, OFT, 1);
    k_inv_h<<<256, 256, 0, stream>>>(OFT, Zre, Zim, AIH, AIL);
    k_invw_skip<1><<<dim3(256, 4), 512, 0, stream>>>(Zre, Zim, nullptr, XBb, TBF,
                                                     WB + 57344, skip_b, XA4, 1);
    k_mlp<1><<<dim3(512, 4), 512, 0, stream>>>(XA4, WB, mlp_b1, mlp_b2, mlp_skip_b, XB4, 1);

    // ---- projection (interleave-4 input) ----
    k_proj<<<dim3(512, 4), 512, 0, stream>>>(XB4, WB, proj_b1, proj_w2, proj_b2,
                                             (float*)d_out);
}